// Round 9
// baseline (2940.838 us; speedup 1.0000x reference)
//
#include <hip/hip_runtime.h>
#include <hip/hip_bf16.h>

#define NB 4
#define NPTS 8192
#define CIN 32
#define COUT 64
#define MOUT 2048   // NPTS / STRIDE
#define KNN 16
#define EPSBN 1e-5f

typedef float f32x2 __attribute__((ext_vector_type(2)));

// ---------------------------------------------------------------------------
// Setup: fold BN into conv weights.  w1s[o][c] = w1[o][c]*a1[o], c1[o]=b1-m1*a1
// wbuf layout (floats): [0,2240) w1s | [2240,2304) c1 | [2304,6400) w2s | [6400,6464) c2
// ---------------------------------------------------------------------------
__global__ void setup_kernel(const float* __restrict__ w1, const float* __restrict__ g1,
                             const float* __restrict__ b1, const float* __restrict__ m1,
                             const float* __restrict__ v1, const float* __restrict__ w2,
                             const float* __restrict__ g2, const float* __restrict__ b2,
                             const float* __restrict__ m2, const float* __restrict__ v2,
                             float* __restrict__ wbuf) {
    int o = threadIdx.x;
    if (o >= 64) return;
    float a1 = g1[o] * rsqrtf(v1[o] + EPSBN);
    wbuf[2240 + o] = b1[o] - m1[o] * a1;
    for (int c = 0; c < 35; ++c) wbuf[o * 35 + c] = w1[o * 35 + c] * a1;
    float a2 = g2[o] * rsqrtf(v2[o] + EPSBN);
    wbuf[6400 + o] = b2[o] - m2[o] * a2;
    for (int c = 0; c < 64; ++c) wbuf[2304 + o * 64 + c] = w2[o * 64 + c] * a2;
}

// ---------------------------------------------------------------------------
// Transpose x (B,C,N) -> xt (B,N,C) with LDS tiles (coalesced both sides)
// ---------------------------------------------------------------------------
__global__ __launch_bounds__(256) void transpose_kernel(const float* __restrict__ x,
                                                        float* __restrict__ xt) {
    __shared__ float tile[CIN][65];
    int b = blockIdx.y;
    int n0 = blockIdx.x * 64;
    int tid = threadIdx.x;
#pragma unroll
    for (int r = 0; r < 8; ++r) {
        int i = r * 256 + tid;
        int c = i >> 6, n = i & 63;
        tile[c][n] = x[((size_t)b * CIN + c) * NPTS + n0 + n];
    }
    __syncthreads();
#pragma unroll
    for (int r = 0; r < 8; ++r) {
        int i = r * 256 + tid;
        int n = i >> 5, c = i & 31;
        xt[((size_t)b * NPTS + n0 + n) * CIN + c] = tile[c][n];
    }
}

// ---------------------------------------------------------------------------
// FPS v6: EXACT spatially-pruned FPS.
// One-time: Morton-bin all points (12-bit cell), LDS counting-sort so each
// thread owns 8 spatially-compact points; per-thread ball (centroid, radius
// inflated x1.001+1e-5) + tb = exact max of its dmin.
// Per iter: wave skips the distance pass iff ALL its lanes satisfy
// (sqrt(dc2)-r)^2 * 0.998 >= tb  (triangle ineq + margins >> fp error ->
// every skipped point provably has d >= dmin, so fminf is a no-op and stored
// dmin stays bit-identical to the sequential reference). Skipped waves reuse
// the cached packed wave-winner (their dmin unchanged -> still exact).
// Argmax: per-lane u64 pack (maxbits<<32)|~origidx, min-orig-idx among
// matching slots, u64 butterfly max intra-wave + across 16 waves ->
// first-occurrence-of-max semantics (== jnp.argmax) at every tie level.
// Distance math identical to reference: (dx*dx+dy*dy)+dz*dz, contract OFF.
// ---------------------------------------------------------------------------
__device__ inline unsigned spread3_4(unsigned v) {
    // v in [0,15] -> bits to positions 0,3,6,9
    return (v & 1u) | ((v & 2u) << 2) | ((v & 4u) << 4) | ((v & 8u) << 6);
}

__global__ __launch_bounds__(1024) void fps_kernel(const float* __restrict__ p1,
                                                   float* __restrict__ p2out) {
#pragma clang fp contract(off)
    int b = blockIdx.x;
    int tid = threadIdx.x;
    int lane = tid & 63;
    int wv = tid >> 6;                        // 0..15
    const float* P = p1 + (size_t)b * NPTS * 3;

    __shared__ float lp[NPTS * 3];            // 96 KiB, ORIGINAL point order
    __shared__ unsigned short mcell[NPTS];    // 16 KiB
    __shared__ unsigned short sidx[NPTS];     // 16 KiB
    __shared__ unsigned int hist[4096];       // 16 KiB
    __shared__ unsigned long long warr[2][16];

    // ---- stage points ----
    const float4* P4 = (const float4*)P;
    float4* L4 = (float4*)lp;
#pragma unroll
    for (int r = 0; r < 6; ++r) {
        int i = r * 1024 + tid;
        L4[i] = P4[i];
    }
#pragma unroll
    for (int k = 0; k < 4; ++k) hist[k * 1024 + tid] = 0u;
    __syncthreads();

    // ---- morton cell + histogram ----
#pragma unroll
    for (int k = 0; k < 8; ++k) {
        int j = k * 1024 + tid;
        float x = lp[3 * j], y = lp[3 * j + 1], z = lp[3 * j + 2];
        int qx = (int)((x + 6.0f) * 1.3333334f);
        int qy = (int)((y + 6.0f) * 1.3333334f);
        int qz = (int)((z + 6.0f) * 1.3333334f);
        qx = qx < 0 ? 0 : (qx > 15 ? 15 : qx);
        qy = qy < 0 ? 0 : (qy > 15 ? 15 : qy);
        qz = qz < 0 ? 0 : (qz > 15 ? 15 : qz);
        unsigned c = spread3_4((unsigned)qx) | (spread3_4((unsigned)qy) << 1) |
                     (spread3_4((unsigned)qz) << 2);
        mcell[j] = (unsigned short)c;
        atomicAdd(&hist[c], 1u);
    }
    __syncthreads();

    // ---- inclusive Hillis-Steele scan over hist[4096] (in place) ----
    for (int off = 1; off < 4096; off <<= 1) {
        unsigned v0, v1, v2, v3;
        {
            int i = tid;
            v0 = hist[i] + ((i >= off) ? hist[i - off] : 0u);
        }
        {
            int i = 1024 + tid;
            v1 = hist[i] + ((i >= off) ? hist[i - off] : 0u);
        }
        {
            int i = 2048 + tid;
            v2 = hist[i] + ((i >= off) ? hist[i - off] : 0u);
        }
        {
            int i = 3072 + tid;
            v3 = hist[i] + ((i >= off) ? hist[i - off] : 0u);
        }
        __syncthreads();
        hist[tid] = v0;
        hist[1024 + tid] = v1;
        hist[2048 + tid] = v2;
        hist[3072 + tid] = v3;
        __syncthreads();
    }

    // ---- scatter: counting sort (order within cell irrelevant) ----
#pragma unroll
    for (int k = 0; k < 8; ++k) {
        int j = k * 1024 + tid;
        unsigned c = mcell[j];
        unsigned pos = atomicSub(&hist[c], 1u) - 1u;
        sidx[pos] = (unsigned short)j;
    }
    __syncthreads();

    // ---- gather 8 sorted points into registers; centroid + radius ----
    int base = tid * 8;
    f32x2 px[4], py[4], pz[4], dmin[4];
    int oid[8];
    float sx = 0.f, sy = 0.f, sz = 0.f;
#pragma unroll
    for (int s = 0; s < 8; ++s) {
        int j = sidx[base + s];
        oid[s] = j;
        float x = lp[3 * j], y = lp[3 * j + 1], z = lp[3 * j + 2];
        if (s & 1) {
            px[s >> 1].y = x; py[s >> 1].y = y; pz[s >> 1].y = z;
        } else {
            px[s >> 1].x = x; py[s >> 1].x = y; pz[s >> 1].x = z;
        }
        sx += x; sy += y; sz += z;
    }
#pragma unroll
    for (int s = 0; s < 4; ++s) {
        dmin[s] = (f32x2){1e10f, 1e10f};
        asm volatile("" : "+v"(px[s]), "+v"(py[s]), "+v"(pz[s]));
    }
#pragma unroll
    for (int s = 0; s < 8; ++s) asm volatile("" : "+v"(oid[s]));
    float cx0 = sx * 0.125f, cy0 = sy * 0.125f, cz0 = sz * 0.125f;
    float r2 = 0.f;
#pragma unroll
    for (int s = 0; s < 4; ++s) {
        f32x2 ax = px[s] - (f32x2){cx0, cx0};
        f32x2 ay = py[s] - (f32x2){cy0, cy0};
        f32x2 az = pz[s] - (f32x2){cz0, cz0};
        f32x2 dd = ax * ax + ay * ay + az * az;
        r2 = fmaxf(r2, fmaxf(dd.x, dd.y));
    }
    float crad = sqrtf(r2) * 1.001f + 1e-5f;
    float tb = 1e10f;
    unsigned long long wavepk = 0ull;

    float lx = lp[0], ly = lp[1], lz = lp[2];
    if (tid == 0) {
        p2out[(size_t)(b * MOUT) * 3 + 0] = lx;
        p2out[(size_t)(b * MOUT) * 3 + 1] = ly;
        p2out[(size_t)(b * MOUT) * 3 + 2] = lz;
    }

    for (int m = 1; m < MOUT; ++m) {
        // ---- wave-level skip test (safe margins; exactness-preserving) ----
        float ddx = cx0 - lx, ddy = cy0 - ly, ddz = cz0 - lz;
        float dc2 = ddx * ddx + ddy * ddy + ddz * ddz;
        float sd = sqrtf(dc2);
        float lbv = sd - crad;
        int upd = !(lbv > 0.0f && lbv * lbv * 0.998f >= tb);
        if (__ballot(upd) != 0ull) {
            // ---- distance pass (exact: mul/add only, in order) ----
            f32x2 lxv = {lx, lx}, lyv = {ly, ly}, lzv = {lz, lz};
#pragma unroll
            for (int s = 0; s < 4; ++s) {
                f32x2 dx = px[s] - lxv;
                f32x2 dy = py[s] - lyv;
                f32x2 dz = pz[s] - lzv;
                f32x2 d = (dx * dx + dy * dy) + dz * dz;
                dmin[s] = __builtin_elementwise_min(dmin[s], d);
            }
            f32x2 t0 = __builtin_elementwise_max(dmin[0], dmin[1]);
            f32x2 t1 = __builtin_elementwise_max(dmin[2], dmin[3]);
            f32x2 u0 = __builtin_elementwise_max(t0, t1);
            float bv = fmaxf(u0.x, u0.y);
            tb = bv;
            unsigned gb = __float_as_uint(bv);
            // smallest ORIGINAL index among slots achieving bv (tree-min)
            int i0 = (__float_as_uint(dmin[0].x) == gb) ? oid[0] : 0x7fffffff;
            int i1 = (__float_as_uint(dmin[0].y) == gb) ? oid[1] : 0x7fffffff;
            int i2 = (__float_as_uint(dmin[1].x) == gb) ? oid[2] : 0x7fffffff;
            int i3 = (__float_as_uint(dmin[1].y) == gb) ? oid[3] : 0x7fffffff;
            int i4 = (__float_as_uint(dmin[2].x) == gb) ? oid[4] : 0x7fffffff;
            int i5 = (__float_as_uint(dmin[2].y) == gb) ? oid[5] : 0x7fffffff;
            int i6 = (__float_as_uint(dmin[3].x) == gb) ? oid[6] : 0x7fffffff;
            int i7 = (__float_as_uint(dmin[3].y) == gb) ? oid[7] : 0x7fffffff;
            int q0 = min(i0, i1), q1 = min(i2, i3);
            int q2 = min(i4, i5), q3 = min(i6, i7);
            int iorig = min(min(q0, q1), min(q2, q3));
            unsigned long long pk =
                ((unsigned long long)gb << 32) | (unsigned)(~iorig);
            // intra-wave u64 butterfly max (ties -> smaller orig idx)
#pragma unroll
            for (int off = 1; off <= 32; off <<= 1) {
                unsigned long long o = __shfl_xor(pk, off);
                if (o > pk) pk = o;
            }
            wavepk = pk;
        }
        if (lane == 0) warr[m & 1][wv] = wavepk;
        __syncthreads();
        // ---- cross-wave: 16 entries, 4-step u64 butterfly ----
        unsigned long long e = warr[m & 1][lane & 15];
#pragma unroll
        for (int off = 1; off <= 8; off <<= 1) {
            unsigned long long o = __shfl_xor(e, off);
            if (o > e) e = o;
        }
        int widx = (int)(~(unsigned)(e & 0xffffffffull));
        int wj = widx * 3;
        lx = lp[wj + 0];
        ly = lp[wj + 1];
        lz = lp[wj + 2];
        if (tid == 0) {
            p2out[((size_t)b * MOUT + m) * 3 + 0] = lx;
            p2out[((size_t)b * MOUT + m) * 3 + 1] = ly;
            p2out[((size_t)b * MOUT + m) * 3 + 2] = lz;
        }
    }
}

// ---------------------------------------------------------------------------
// kNN: one wave per query. Distributed sorted top-16 in lanes 0..15,
// ballot-compacted insertion. d2 mirrors reference formula exactly.
// ---------------------------------------------------------------------------
__global__ __launch_bounds__(256) void knn_kernel(const float* __restrict__ p1,
                                                  const float* __restrict__ p2,
                                                  int* __restrict__ nnout) {
    int tid = threadIdx.x;
    int lane = tid & 63, wid = tid >> 6;
    int qid = blockIdx.x * 4 + wid;          // 0..8191
    int b = qid >> 11;
    const float* Pb = p1 + (size_t)b * NPTS * 3;
    const float* q = p2 + (size_t)qid * 3;
    float qx = q[0], qy = q[1], qz = q[2];
    float s2q = __fadd_rn(__fadd_rn(__fmul_rn(qx, qx), __fmul_rn(qy, qy)),
                          __fmul_rn(qz, qz));

    float tval = 3.0e38f;   // distributed sorted list (lanes 0..15)
    int   tidx = -1;
    float tau = 3.0e38f;

    for (int n0 = 0; n0 < NPTS; n0 += 64) {
        int n = n0 + lane;
        const float* pp = Pb + n * 3;
        float px = pp[0], py = pp[1], pz = pp[2];
        float s1n = __fadd_rn(__fadd_rn(__fmul_rn(px, px), __fmul_rn(py, py)),
                              __fmul_rn(pz, pz));
        float dot = __fadd_rn(__fadd_rn(__fmul_rn(qx, px), __fmul_rn(qy, py)),
                              __fmul_rn(qz, pz));
        float d2 = __fsub_rn(__fadd_rn(s2q, s1n), __fmul_rn(2.0f, dot));

        unsigned long long act = __ballot(d2 < tau);
        while (act) {
            int l = __ffsll(act) - 1;
            float dd = __shfl(d2, l);
            int   nn_ = __shfl(n, l);
            unsigned long long mle = __ballot(lane < 16 && tval <= dd);
            int pos = __popcll(mle);                 // stable insert position
            float sv = __shfl_up(tval, 1);
            int   si = __shfl_up(tidx, 1);
            if (lane < 16) {
                if (lane == pos)      { tval = dd; tidx = nn_; }
                else if (lane > pos)  { tval = sv; tidx = si; }
            }
            tau = __shfl(tval, 15);
            act &= (act - 1);
            act &= __ballot(d2 < tau);
        }
    }
    if (lane < 16) nnout[(size_t)qid * KNN + lane] = tidx;
}

// ---------------------------------------------------------------------------
// Fused gather + conv1(BN-folded)+ReLU + conv2(BN-folded)+ReLU + max over K.
// ---------------------------------------------------------------------------
template <int XT>
__global__ __launch_bounds__(256) void conv_kernel(const float* __restrict__ p1,
                                                   const float* __restrict__ p2,
                                                   const float* __restrict__ xsrc,
                                                   const int* __restrict__ nn,
                                                   const float* __restrict__ wbuf,
                                                   float* __restrict__ y) {
    const float* w1s = wbuf;
    const float* c1s = wbuf + 2240;
    const float* w2s = wbuf + 2304;
    const float* c2s = wbuf + 6400;
    int tid = threadIdx.x;
    int lane = tid & 63, wid = tid >> 6;
    int qq = lane >> 4, k = lane & 15;
    int qid = (blockIdx.x * 4 + wid) * 4 + qq;   // 0..8191
    int b = qid >> 11, m = qid & 2047;
    int nk = nn[(size_t)qid * KNN + k];

    const float* qp = p2 + (size_t)qid * 3;
    const float* np = p1 + ((size_t)b * NPTS + nk) * 3;
    float h[35];
    h[0] = np[0] - qp[0];
    h[1] = np[1] - qp[1];
    h[2] = np[2] - qp[2];
    if (XT) {
        const float4* xr = (const float4*)(xsrc + ((size_t)b * NPTS + nk) * CIN);
#pragma unroll
        for (int q8 = 0; q8 < 8; ++q8) {
            float4 f = xr[q8];
            h[3 + q8 * 4 + 0] = f.x;
            h[3 + q8 * 4 + 1] = f.y;
            h[3 + q8 * 4 + 2] = f.z;
            h[3 + q8 * 4 + 3] = f.w;
        }
    } else {
#pragma unroll
        for (int c = 0; c < CIN; ++c)
            h[3 + c] = xsrc[((size_t)b * CIN + c) * NPTS + nk];
    }

    float acc2[64];
#pragma unroll
    for (int o2 = 0; o2 < 64; ++o2) acc2[o2] = c2s[o2];

    for (int o = 0; o < 64; ++o) {
        float a = c1s[o];
#pragma unroll
        for (int c = 0; c < 35; ++c) a = fmaf(h[c], w1s[o * 35 + c], a);
        a = fmaxf(a, 0.0f);
#pragma unroll
        for (int o2 = 0; o2 < 64; ++o2) acc2[o2] = fmaf(a, w2s[o2 * 64 + o], acc2[o2]);
    }

#pragma unroll
    for (int o2 = 0; o2 < 64; ++o2) {
        float v = fmaxf(acc2[o2], 0.0f);
        v = fmaxf(v, __shfl_xor(v, 8));
        v = fmaxf(v, __shfl_xor(v, 4));
        v = fmaxf(v, __shfl_xor(v, 2));
        v = fmaxf(v, __shfl_xor(v, 1));
        if ((lane & 15) == (o2 & 15))
            y[((size_t)b * COUT + o2) * MOUT + m] = v;
    }
}

// ---------------------------------------------------------------------------
extern "C" void kernel_launch(void* const* d_in, const int* in_sizes, int n_in,
                              void* d_out, int out_size, void* d_ws, size_t ws_size,
                              hipStream_t stream) {
    const float* p1 = (const float*)d_in[0];
    const float* x  = (const float*)d_in[1];
    const float* w1 = (const float*)d_in[2];
    const float* g1 = (const float*)d_in[3];
    const float* b1 = (const float*)d_in[4];
    const float* m1 = (const float*)d_in[5];
    const float* v1 = (const float*)d_in[6];
    const float* w2 = (const float*)d_in[7];
    const float* g2 = (const float*)d_in[8];
    const float* b2 = (const float*)d_in[9];
    const float* m2 = (const float*)d_in[10];
    const float* v2 = (const float*)d_in[11];

    float* p2o = (float*)d_out;                       // (B,M,3)
    float* yo  = p2o + (size_t)NB * MOUT * 3;         // (B,COUT,M)

    char* ws = (char*)d_ws;
    int*   nn   = (int*)ws;                            // 512 KiB
    float* wbuf = (float*)(ws + 512 * 1024);           // 25.9 KiB
    float* xt   = (float*)(ws + 1024 * 1024);          // 4 MiB
    bool use_xt = ws_size >= (size_t)(1024 * 1024) + (size_t)NB * NPTS * CIN * 4;

    setup_kernel<<<1, 64, 0, stream>>>(w1, g1, b1, m1, v1, w2, g2, b2, m2, v2, wbuf);
    if (use_xt)
        transpose_kernel<<<dim3(NPTS / 64, NB), 256, 0, stream>>>(x, xt);
    fps_kernel<<<NB, 1024, 0, stream>>>(p1, p2o);
    knn_kernel<<<(NB * MOUT) / 4, 256, 0, stream>>>(p1, p2o, nn);
    if (use_xt)
        conv_kernel<1><<<(NB * MOUT) / 16, 256, 0, stream>>>(p1, p2o, xt, nn, wbuf, yo);
    else
        conv_kernel<0><<<(NB * MOUT) / 16, 256, 0, stream>>>(p1, p2o, x, nn, wbuf, yo);
}

// Round 10
// 2265.398 us; speedup vs baseline: 1.2982x; 1.2982x over previous
//
#include <hip/hip_runtime.h>
#include <hip/hip_bf16.h>

#define NB 4
#define NPTS 8192
#define CIN 32
#define COUT 64
#define MOUT 2048   // NPTS / STRIDE
#define KNN 16
#define EPSBN 1e-5f

// ---------------------------------------------------------------------------
// Setup: fold BN into conv weights.  w1s[o][c] = w1[o][c]*a1[o], c1[o]=b1-m1*a1
// wbuf layout (floats): [0,2240) w1s | [2240,2304) c1 | [2304,6400) w2s | [6400,6464) c2
// ---------------------------------------------------------------------------
__global__ void setup_kernel(const float* __restrict__ w1, const float* __restrict__ g1,
                             const float* __restrict__ b1, const float* __restrict__ m1,
                             const float* __restrict__ v1, const float* __restrict__ w2,
                             const float* __restrict__ g2, const float* __restrict__ b2,
                             const float* __restrict__ m2, const float* __restrict__ v2,
                             float* __restrict__ wbuf) {
    int o = threadIdx.x;
    if (o >= 64) return;
    float a1 = g1[o] * rsqrtf(v1[o] + EPSBN);
    wbuf[2240 + o] = b1[o] - m1[o] * a1;
    for (int c = 0; c < 35; ++c) wbuf[o * 35 + c] = w1[o * 35 + c] * a1;
    float a2 = g2[o] * rsqrtf(v2[o] + EPSBN);
    wbuf[6400 + o] = b2[o] - m2[o] * a2;
    for (int c = 0; c < 64; ++c) wbuf[2304 + o * 64 + c] = w2[o * 64 + c] * a2;
}

// ---------------------------------------------------------------------------
// Transpose x (B,C,N) -> xt (B,N,C) with LDS tiles (coalesced both sides)
// ---------------------------------------------------------------------------
__global__ __launch_bounds__(256) void transpose_kernel(const float* __restrict__ x,
                                                        float* __restrict__ xt) {
    __shared__ float tile[CIN][65];
    int b = blockIdx.y;
    int n0 = blockIdx.x * 64;
    int tid = threadIdx.x;
#pragma unroll
    for (int r = 0; r < 8; ++r) {
        int i = r * 256 + tid;
        int c = i >> 6, n = i & 63;
        tile[c][n] = x[((size_t)b * CIN + c) * NPTS + n0 + n];
    }
    __syncthreads();
#pragma unroll
    for (int r = 0; r < 8; ++r) {
        int i = r * 256 + tid;
        int n = i >> 5, c = i & 31;
        xt[((size_t)b * NPTS + n0 + n) * CIN + c] = tile[c][n];
    }
}

// ---------------------------------------------------------------------------
// FPS v7: 512 threads/block, 16 pts/thread in SCALAR register arrays, pinned
// per-element (the r3-proven residency pattern; v5/v6's f32x2 arrays were
// silently rebuilt from LDS every iter -- VGPR_Count 52 < 64 proved it).
// No Morton, no skip (r9 post-mortem: skip never fired, pure overhead).
// Points staged in LDS only for init + winner broadcast.
// Exactness: d = (dx*dx+dy*dy)+dz*dz via __f*_rn (no contraction);
// argmax = first occurrence of max: value-only DPP butterfly, then
// descending-slot bit-equality scan (smallest slot), ballot (smallest lane),
// u64 pack (val<<32)|~idx across waves (smallest index). Distances >= 0 so
// bit-equality == float equality.
// ---------------------------------------------------------------------------
#define FPS_PT 16
__global__ __launch_bounds__(512) void fps_kernel(const float* __restrict__ p1,
                                                  float* __restrict__ p2out) {
    int b = blockIdx.x;
    int tid = threadIdx.x;
    int lane = tid & 63;
    int wv = tid >> 6;                        // 0..7
    const float* P = p1 + (size_t)b * NPTS * 3;

    __shared__ float lp[NPTS * 3];            // 96 KiB point stage
    __shared__ unsigned long long warr[2][8];

    const float4* P4 = (const float4*)P;
    float4* L4 = (float4*)lp;
#pragma unroll
    for (int r = 0; r < 12; ++r) {
        int i = r * 512 + tid;
        L4[i] = P4[i];
    }
    __syncthreads();

    float px[FPS_PT], py[FPS_PT], pz[FPS_PT], dmin[FPS_PT];
    int base = tid * FPS_PT;
#pragma unroll
    for (int s = 0; s < FPS_PT; ++s) {
        int j = (base + s) * 3;
        px[s] = lp[j + 0];
        py[s] = lp[j + 1];
        pz[s] = lp[j + 2];
        dmin[s] = 1e10f;
        // pin: opaque producer -> compiler cannot re-load from LDS in the loop
        asm volatile("" : "+v"(px[s]), "+v"(py[s]), "+v"(pz[s]));
    }

    float lx = lp[0], ly = lp[1], lz = lp[2];
    if (tid == 0) {
        p2out[(size_t)(b * MOUT) * 3 + 0] = lx;
        p2out[(size_t)(b * MOUT) * 3 + 1] = ly;
        p2out[(size_t)(b * MOUT) * 3 + 2] = lz;
    }

    for (int m = 1; m < MOUT; ++m) {
        // ---- phase A: update dmin (exact mul/add order), collect nd ----
        float nd[FPS_PT];
#pragma unroll
        for (int s = 0; s < FPS_PT; ++s) {
            float dx = __fsub_rn(px[s], lx);
            float dy = __fsub_rn(py[s], ly);
            float dz = __fsub_rn(pz[s], lz);
            float d = __fadd_rn(__fadd_rn(__fmul_rn(dx, dx), __fmul_rn(dy, dy)),
                                __fmul_rn(dz, dz));
            float t = fminf(dmin[s], d);
            dmin[s] = t;
            nd[s] = t;
        }
        // ---- explicit fmax tree (depth 4) ----
        float a0 = fmaxf(nd[0], nd[1]),   a1 = fmaxf(nd[2], nd[3]);
        float a2 = fmaxf(nd[4], nd[5]),   a3 = fmaxf(nd[6], nd[7]);
        float a4 = fmaxf(nd[8], nd[9]),   a5 = fmaxf(nd[10], nd[11]);
        float a6 = fmaxf(nd[12], nd[13]), a7 = fmaxf(nd[14], nd[15]);
        float b0 = fmaxf(a0, a1), b1 = fmaxf(a2, a3);
        float b2 = fmaxf(a4, a5), b3 = fmaxf(a6, a7);
        float bv = fmaxf(fmaxf(b0, b1), fmaxf(b2, b3));
        // ---- wave value-max: 4x DPP row_shr + xor16 swizzle + xor32 ----
        float x0 = bv;
        {
            int xi, sh;
            xi = __float_as_int(x0);
            sh = __builtin_amdgcn_update_dpp(xi, xi, 0x111, 0xF, 0xF, false);
            x0 = fmaxf(x0, __int_as_float(sh));
            xi = __float_as_int(x0);
            sh = __builtin_amdgcn_update_dpp(xi, xi, 0x112, 0xF, 0xF, false);
            x0 = fmaxf(x0, __int_as_float(sh));
            xi = __float_as_int(x0);
            sh = __builtin_amdgcn_update_dpp(xi, xi, 0x114, 0xF, 0xF, false);
            x0 = fmaxf(x0, __int_as_float(sh));
            xi = __float_as_int(x0);
            sh = __builtin_amdgcn_update_dpp(xi, xi, 0x118, 0xF, 0xF, false);
            x0 = fmaxf(x0, __int_as_float(sh));
            x0 = fmaxf(x0, __int_as_float(
                     __builtin_amdgcn_ds_swizzle(__float_as_int(x0), 0x401F)));
            x0 = fmaxf(x0, __shfl_xor(x0, 32));
        }
        unsigned g = (unsigned)__builtin_amdgcn_readlane(__float_as_int(x0), 15);
        // ---- index recovery: first (lane, slot) with bits(dmin)==g ----
        int loc = FPS_PT;
#pragma unroll
        for (int s = FPS_PT - 1; s >= 0; --s)
            if (__float_as_uint(dmin[s]) == g) loc = s;
        unsigned long long bal = __ballot(loc < FPS_PT);
        int l = __ffsll((long long)bal) - 1;
        int widx_w = __shfl(base + loc, l);
        // ---- cross-wave: per-wave slot write + 3-step u64 butterfly ----
        int par = m & 1;
        if (lane == 0) {
            unsigned long long pk =
                ((unsigned long long)g << 32) | (unsigned long long)(unsigned)(~widx_w);
            warr[par][wv] = pk;
        }
        __syncthreads();
        unsigned long long e = warr[par][lane & 7];
#pragma unroll
        for (int off = 1; off <= 4; off <<= 1) {
            unsigned long long o = __shfl_xor(e, off);
            if (o > e) e = o;
        }
        int widx = (int)(~(unsigned)(e & 0xffffffffull));
        int wj = widx * 3;
        lx = lp[wj + 0];
        ly = lp[wj + 1];
        lz = lp[wj + 2];
        if (tid == 0) {
            p2out[((size_t)b * MOUT + m) * 3 + 0] = lx;
            p2out[((size_t)b * MOUT + m) * 3 + 1] = ly;
            p2out[((size_t)b * MOUT + m) * 3 + 2] = lz;
        }
    }
}

// ---------------------------------------------------------------------------
// kNN: one wave per query. Distributed sorted top-16 in lanes 0..15,
// ballot-compacted insertion. d2 mirrors reference formula exactly.
// ---------------------------------------------------------------------------
__global__ __launch_bounds__(256) void knn_kernel(const float* __restrict__ p1,
                                                  const float* __restrict__ p2,
                                                  int* __restrict__ nnout) {
    int tid = threadIdx.x;
    int lane = tid & 63, wid = tid >> 6;
    int qid = blockIdx.x * 4 + wid;          // 0..8191
    int b = qid >> 11;
    const float* Pb = p1 + (size_t)b * NPTS * 3;
    const float* q = p2 + (size_t)qid * 3;
    float qx = q[0], qy = q[1], qz = q[2];
    float s2q = __fadd_rn(__fadd_rn(__fmul_rn(qx, qx), __fmul_rn(qy, qy)),
                          __fmul_rn(qz, qz));

    float tval = 3.0e38f;   // distributed sorted list (lanes 0..15)
    int   tidx = -1;
    float tau = 3.0e38f;

    for (int n0 = 0; n0 < NPTS; n0 += 64) {
        int n = n0 + lane;
        const float* pp = Pb + n * 3;
        float px = pp[0], py = pp[1], pz = pp[2];
        float s1n = __fadd_rn(__fadd_rn(__fmul_rn(px, px), __fmul_rn(py, py)),
                              __fmul_rn(pz, pz));
        float dot = __fadd_rn(__fadd_rn(__fmul_rn(qx, px), __fmul_rn(qy, py)),
                              __fmul_rn(qz, pz));
        float d2 = __fsub_rn(__fadd_rn(s2q, s1n), __fmul_rn(2.0f, dot));

        unsigned long long act = __ballot(d2 < tau);
        while (act) {
            int l = __ffsll(act) - 1;
            float dd = __shfl(d2, l);
            int   nn_ = __shfl(n, l);
            unsigned long long mle = __ballot(lane < 16 && tval <= dd);
            int pos = __popcll(mle);                 // stable insert position
            float sv = __shfl_up(tval, 1);
            int   si = __shfl_up(tidx, 1);
            if (lane < 16) {
                if (lane == pos)      { tval = dd; tidx = nn_; }
                else if (lane > pos)  { tval = sv; tidx = si; }
            }
            tau = __shfl(tval, 15);
            act &= (act - 1);
            act &= __ballot(d2 < tau);
        }
    }
    if (lane < 16) nnout[(size_t)qid * KNN + lane] = tidx;
}

// ---------------------------------------------------------------------------
// Fused gather + conv1(BN-folded)+ReLU + conv2(BN-folded)+ReLU + max over K.
// ---------------------------------------------------------------------------
template <int XT>
__global__ __launch_bounds__(256) void conv_kernel(const float* __restrict__ p1,
                                                   const float* __restrict__ p2,
                                                   const float* __restrict__ xsrc,
                                                   const int* __restrict__ nn,
                                                   const float* __restrict__ wbuf,
                                                   float* __restrict__ y) {
    const float* w1s = wbuf;
    const float* c1s = wbuf + 2240;
    const float* w2s = wbuf + 2304;
    const float* c2s = wbuf + 6400;
    int tid = threadIdx.x;
    int lane = tid & 63, wid = tid >> 6;
    int qq = lane >> 4, k = lane & 15;
    int qid = (blockIdx.x * 4 + wid) * 4 + qq;   // 0..8191
    int b = qid >> 11, m = qid & 2047;
    int nk = nn[(size_t)qid * KNN + k];

    const float* qp = p2 + (size_t)qid * 3;
    const float* np = p1 + ((size_t)b * NPTS + nk) * 3;
    float h[35];
    h[0] = np[0] - qp[0];
    h[1] = np[1] - qp[1];
    h[2] = np[2] - qp[2];
    if (XT) {
        const float4* xr = (const float4*)(xsrc + ((size_t)b * NPTS + nk) * CIN);
#pragma unroll
        for (int q8 = 0; q8 < 8; ++q8) {
            float4 f = xr[q8];
            h[3 + q8 * 4 + 0] = f.x;
            h[3 + q8 * 4 + 1] = f.y;
            h[3 + q8 * 4 + 2] = f.z;
            h[3 + q8 * 4 + 3] = f.w;
        }
    } else {
#pragma unroll
        for (int c = 0; c < CIN; ++c)
            h[3 + c] = xsrc[((size_t)b * CIN + c) * NPTS + nk];
    }

    float acc2[64];
#pragma unroll
    for (int o2 = 0; o2 < 64; ++o2) acc2[o2] = c2s[o2];

    for (int o = 0; o < 64; ++o) {
        float a = c1s[o];
#pragma unroll
        for (int c = 0; c < 35; ++c) a = fmaf(h[c], w1s[o * 35 + c], a);
        a = fmaxf(a, 0.0f);
#pragma unroll
        for (int o2 = 0; o2 < 64; ++o2) acc2[o2] = fmaf(a, w2s[o2 * 64 + o], acc2[o2]);
    }

#pragma unroll
    for (int o2 = 0; o2 < 64; ++o2) {
        float v = fmaxf(acc2[o2], 0.0f);
        v = fmaxf(v, __shfl_xor(v, 8));
        v = fmaxf(v, __shfl_xor(v, 4));
        v = fmaxf(v, __shfl_xor(v, 2));
        v = fmaxf(v, __shfl_xor(v, 1));
        if ((lane & 15) == (o2 & 15))
            y[((size_t)b * COUT + o2) * MOUT + m] = v;
    }
}

// ---------------------------------------------------------------------------
extern "C" void kernel_launch(void* const* d_in, const int* in_sizes, int n_in,
                              void* d_out, int out_size, void* d_ws, size_t ws_size,
                              hipStream_t stream) {
    const float* p1 = (const float*)d_in[0];
    const float* x  = (const float*)d_in[1];
    const float* w1 = (const float*)d_in[2];
    const float* g1 = (const float*)d_in[3];
    const float* b1 = (const float*)d_in[4];
    const float* m1 = (const float*)d_in[5];
    const float* v1 = (const float*)d_in[6];
    const float* w2 = (const float*)d_in[7];
    const float* g2 = (const float*)d_in[8];
    const float* b2 = (const float*)d_in[9];
    const float* m2 = (const float*)d_in[10];
    const float* v2 = (const float*)d_in[11];

    float* p2o = (float*)d_out;                       // (B,M,3)
    float* yo  = p2o + (size_t)NB * MOUT * 3;         // (B,COUT,M)

    char* ws = (char*)d_ws;
    int*   nn   = (int*)ws;                            // 512 KiB
    float* wbuf = (float*)(ws + 512 * 1024);           // 25.9 KiB
    float* xt   = (float*)(ws + 1024 * 1024);          // 4 MiB
    bool use_xt = ws_size >= (size_t)(1024 * 1024) + (size_t)NB * NPTS * CIN * 4;

    setup_kernel<<<1, 64, 0, stream>>>(w1, g1, b1, m1, v1, w2, g2, b2, m2, v2, wbuf);
    if (use_xt)
        transpose_kernel<<<dim3(NPTS / 64, NB), 256, 0, stream>>>(x, xt);
    fps_kernel<<<NB, 512, 0, stream>>>(p1, p2o);
    knn_kernel<<<(NB * MOUT) / 4, 256, 0, stream>>>(p1, p2o, nn);
    if (use_xt)
        conv_kernel<1><<<(NB * MOUT) / 16, 256, 0, stream>>>(p1, p2o, xt, nn, wbuf, yo);
    else
        conv_kernel<0><<<(NB * MOUT) / 16, 256, 0, stream>>>(p1, p2o, x, nn, wbuf, yo);
}